// Round 1
// baseline (217.941 us; speedup 1.0000x reference)
//
#include <hip/hip_runtime.h>
#include <hip/hip_bf16.h>
#include <stdint.h>

typedef unsigned short u16;
typedef __attribute__((ext_vector_type(8))) short short8_t;
typedef __attribute__((ext_vector_type(4))) float f32x4;

#define D_DIM 512
#define K_CL  256
#define BM    128

__device__ __forceinline__ u16 f2bf(float f) {
  union { float f; uint32_t u; } v; v.f = f;
  uint32_t r = v.u + 0x7fffu + ((v.u >> 16) & 1u);  // RNE
  return (u16)(r >> 16);
}

// prep: clusters fp32 [256][512] -> bf16 cb [256][512] + csq[256] (fp32 norms)
__global__ void prep_kernel(const float* __restrict__ clusters,
                            u16* __restrict__ cb, float* __restrict__ csq) {
  int k = blockIdx.x;
  int t = threadIdx.x;  // 128 threads, 4 floats each
  float4 f = ((const float4*)(clusters + (size_t)k * D_DIM))[t];
  ushort4 u;
  u.x = f2bf(f.x); u.y = f2bf(f.y); u.z = f2bf(f.z); u.w = f2bf(f.w);
  ((ushort4*)(cb + (size_t)k * D_DIM))[t] = u;
  float s = f.x*f.x + f.y*f.y + f.z*f.z + f.w*f.w;
  #pragma unroll
  for (int m = 1; m < 64; m <<= 1) s += __shfl_xor(s, m, 64);
  __shared__ float part[2];
  if ((t & 63) == 0) part[t >> 6] = s;
  __syncthreads();
  if (t == 0) csq[k] = part[0] + part[1];
}

// main: 128-row x 256-col tile per block; bf16 MFMA; fused Student-t + row-norm
__global__ __launch_bounds__(512)
void cluster_kernel(const float* __restrict__ x,
                    const u16* __restrict__ cb,
                    const float* __restrict__ csq,
                    float* __restrict__ out) {
  __shared__ u16  lA[BM * 32];        // 8 KB
  __shared__ u16  lB[K_CL * 32];      // 16 KB
  __shared__ float xsq_lds[BM];
  __shared__ float csq_lds[K_CL];
  __shared__ float rowsum[4 * BM];    // [wave_n][row]

  const int tid   = threadIdx.x;
  const int lane  = tid & 63;
  const int w     = tid >> 6;
  const int quad  = lane >> 4;
  const int l16   = lane & 15;
  const int wave_m = w >> 2;          // 0..1  (row half)
  const int wave_n = w & 3;           // 0..3  (col quarter)
  const int row0  = blockIdx.x * BM;

  if (tid < K_CL) csq_lds[tid] = csq[tid];

  // A staging: thread -> (row ar, col segment ac), 8 floats/step
  const int ar = tid >> 2;            // 0..127
  const int ac = (tid & 3) * 8;       // 0,8,16,24
  const float* xg = x + (size_t)(row0 + ar) * D_DIM + ac;
  short8_t* aw = (short8_t*)&lA[ar * 32 + ac];

  // fragment read offsets (ushort indices)
  const int aro = (wave_m * 64 + l16) * 32 + quad * 8;
  const int bro = (wave_n * 64 + l16) * 32 + quad * 8;

  f32x4 acc[4][4];
  #pragma unroll
  for (int i = 0; i < 4; ++i)
    #pragma unroll
    for (int j = 0; j < 4; ++j)
      acc[i][j] = (f32x4){0.f, 0.f, 0.f, 0.f};

  float sq = 0.f;
  const int boff0 = tid * 16;         // byte offset into 16KB B tile

  for (int kk = 0; kk < D_DIM; kk += 32) {
    if (kk) __syncthreads();
    // ---- stage A: fp32 load -> bf16 -> LDS (x_sq accumulated for free) ----
    float4 f0 = *(const float4*)(xg + kk);
    float4 f1 = *(const float4*)(xg + kk + 4);
    sq += f0.x*f0.x + f0.y*f0.y + f0.z*f0.z + f0.w*f0.w
        + f1.x*f1.x + f1.y*f1.y + f1.z*f1.z + f1.w*f1.w;
    union { u16 u[8]; short8_t v; } pk;
    pk.u[0]=f2bf(f0.x); pk.u[1]=f2bf(f0.y); pk.u[2]=f2bf(f0.z); pk.u[3]=f2bf(f0.w);
    pk.u[4]=f2bf(f1.x); pk.u[5]=f2bf(f1.y); pk.u[6]=f2bf(f1.z); pk.u[7]=f2bf(f1.w);
    *aw = pk.v;
    // ---- stage B: async global->LDS, 16B/lane, 2 issues ----
    #pragma unroll
    for (int i = 0; i < 2; ++i) {
      int off = boff0 + i * 8192;                 // byte offset in tile
      int n = off >> 6;                           // cluster row (64B per row-chunk)
      int inrow = off & 63;
      const u16* src = cb + (size_t)n * D_DIM + kk + (inrow >> 1);
      __builtin_amdgcn_global_load_lds(
          (const __attribute__((address_space(1))) void*)src,
          (__attribute__((address_space(3))) void*)((char*)lB + off),
          16, 0, 0);
    }
    __syncthreads();
    // ---- fragments + 16 MFMA ----
    short8_t aF[4], bF[4];
    #pragma unroll
    for (int mi = 0; mi < 4; ++mi)
      aF[mi] = *(const short8_t*)&lA[aro + mi * 16 * 32];
    #pragma unroll
    for (int ni = 0; ni < 4; ++ni)
      bF[ni] = *(const short8_t*)&lB[bro + ni * 16 * 32];
    #pragma unroll
    for (int mi = 0; mi < 4; ++mi)
      #pragma unroll
      for (int ni = 0; ni < 4; ++ni)
        acc[mi][ni] = __builtin_amdgcn_mfma_f32_16x16x32_bf16(
            aF[mi], bF[ni], acc[mi][ni], 0, 0, 0);
  }

  // x_sq: reduce the 4 staging threads of each row (consecutive lanes)
  sq += __shfl_xor(sq, 1, 64);
  sq += __shfl_xor(sq, 2, 64);
  if ((tid & 3) == 0) xsq_lds[ar] = sq;
  __syncthreads();

  // ---- epilogue: Student-t + per-row partial sums ----
  #pragma unroll
  for (int mi = 0; mi < 4; ++mi) {
    #pragma unroll
    for (int v = 0; v < 4; ++v) {
      int row = wave_m * 64 + mi * 16 + quad * 4 + v;
      float xs = xsq_lds[row];
      float s = 0.f;
      #pragma unroll
      for (int ni = 0; ni < 4; ++ni) {
        int col = wave_n * 64 + ni * 16 + l16;
        float d = xs + csq_lds[col] - 2.0f * acc[mi][ni][v];
        d = fmaxf(d, 0.f);
        float q = 1.0f / (1.0f + d);   // alpha=1: (1+d^2)^-1
        acc[mi][ni][v] = q;
        s += q;
      }
      // sum across the 16 lanes of this quad (disjoint 64 cols of wave tile)
      s += __shfl_xor(s, 1, 64);
      s += __shfl_xor(s, 2, 64);
      s += __shfl_xor(s, 4, 64);
      s += __shfl_xor(s, 8, 64);
      if (l16 == 0) rowsum[wave_n * BM + row] = s;
    }
  }
  __syncthreads();

  // ---- normalize + store ----
  #pragma unroll
  for (int mi = 0; mi < 4; ++mi) {
    #pragma unroll
    for (int v = 0; v < 4; ++v) {
      int row = wave_m * 64 + mi * 16 + quad * 4 + v;
      float tot = rowsum[row] + rowsum[BM + row] + rowsum[2*BM + row] + rowsum[3*BM + row];
      float inv = 1.0f / tot;
      float* orow = out + (size_t)(row0 + row) * K_CL;
      #pragma unroll
      for (int ni = 0; ni < 4; ++ni) {
        int col = wave_n * 64 + ni * 16 + l16;
        orow[col] = acc[mi][ni][v] * inv;
      }
    }
  }
}

extern "C" void kernel_launch(void* const* d_in, const int* in_sizes, int n_in,
                              void* d_out, int out_size, void* d_ws, size_t ws_size,
                              hipStream_t stream) {
  const float* x        = (const float*)d_in[0];
  const float* clusters = (const float*)d_in[1];
  float* out = (float*)d_out;
  const int N = in_sizes[0] / D_DIM;   // 65536

  u16*   cb  = (u16*)d_ws;                                    // 256*512*2 = 256 KB
  float* csq = (float*)((char*)d_ws + (size_t)K_CL * D_DIM * sizeof(u16));

  prep_kernel<<<K_CL, 128, 0, stream>>>(clusters, cb, csq);
  cluster_kernel<<<N / BM, 512, 0, stream>>>(x, cb, csq, out);
}